// Round 1
// 669.482 us; speedup vs baseline: 1.1397x; 1.1397x over previous
//
#include <hip/hip_runtime.h>

#define NB 512
#define NC 3
#define NP_ 49
#define NT_ 76
#define DD 768

typedef __attribute__((ext_vector_type(8))) short bf16x8;
typedef __attribute__((ext_vector_type(4))) float f32x4;

__device__ inline unsigned short f2bf(float x) {
    unsigned int u = __float_as_uint(x);
    u += 0x7FFFu + ((u >> 16) & 1u);   // RNE to bf16
    return (unsigned short)(u >> 16);
}
__device__ inline float bfval(unsigned short s) {
    return __uint_as_float((unsigned int)s << 16);
}
__device__ inline float f4get(const float4& v, int e) {
    return e == 0 ? v.x : e == 1 ? v.y : e == 2 ? v.z : v.w;
}

// convert 8 fp32 -> bf16x8 (RNE), accumulate squared-norm of the bf16 values
__device__ inline bf16x8 pack8(const float4& lo, const float4& hi, float& nrm) {
    bf16x8 r;
    unsigned short s; float x;
    s = f2bf(lo.x); x = bfval(s); nrm += x * x; r[0] = (short)s;
    s = f2bf(lo.y); x = bfval(s); nrm += x * x; r[1] = (short)s;
    s = f2bf(lo.z); x = bfval(s); nrm += x * x; r[2] = (short)s;
    s = f2bf(lo.w); x = bfval(s); nrm += x * x; r[3] = (short)s;
    s = f2bf(hi.x); x = bfval(s); nrm += x * x; r[4] = (short)s;
    s = f2bf(hi.y); x = bfval(s); nrm += x * x; r[5] = (short)s;
    s = f2bf(hi.z); x = bfval(s); nrm += x * x; r[6] = (short)s;
    s = f2bf(hi.w); x = bfval(s); nrm += x * x; r[7] = (short)s;
    return r;
}

// ---------------------------------------------------------------------------
// Kernel 1: ONE WAVE per (b,ch).  grid = 1536, block = 64.  No __syncthreads.
//   - MFMA fragments loaded straight from global (fp32) -> bf16 regs
//   - norms accumulated in-register during conversion
//   - Sinkhorn fully wave-private: K row + K columns in registers,
//     c in LDS (b128 broadcast reads), r broadcast via LDS b128.
// ---------------------------------------------------------------------------
__global__ __launch_bounds__(64, 2) void sink_kernel(const float* __restrict__ lif,
                                                     const float* __restrict__ ltf,
                                                     float* __restrict__ out) {
    const int lane = threadIdx.x;          // 0..63
    const int bc   = blockIdx.x;           // b*3 + ch
    const int lr = lane & 15, lk = lane >> 4;
    const float* ga = lif + (size_t)bc * (NP_ * DD);
    const float* gb = ltf + (size_t)bc * (NT_ * DD);

    __shared__ float Kmat[NP_ * 77];                       // stride 77: b32 reads 2-way max
    __shared__ __attribute__((aligned(16))) float c_vec[80];
    __shared__ __attribute__((aligned(16))) float r_vec[64];

    // fragment row pointers (rows clamped; clamped rows only feed n>=49 / m>=76,
    // which are discarded)
    const float* pa[4];
#pragma unroll
    for (int tn = 0; tn < 4; ++tn) {
        int row = tn * 16 + lr; if (row > NP_ - 1) row = NP_ - 1;
        pa[tn] = ga + row * DD + lk * 8;
    }
    const float* pb[5];
#pragma unroll
    for (int j = 0; j < 5; ++j) {
        int row = j * 16 + lr; if (row > NT_ - 1) row = NT_ - 1;
        pb[j] = gb + row * DD + lk * 8;
    }

    f32x4 acc[4][5];
    const f32x4 zero4 = {0.f, 0.f, 0.f, 0.f};
#pragma unroll
    for (int tn = 0; tn < 4; ++tn)
#pragma unroll
        for (int j = 0; j < 5; ++j) acc[tn][j] = zero4;
    float na[4] = {0.f, 0.f, 0.f, 0.f};
    float nb[5] = {0.f, 0.f, 0.f, 0.f, 0.f};

    // ---- GEMM phase: 24 K-steps of 32, same K order as before -> acc bit-identical
#pragma unroll 1
    for (int cc = 0; cc < 24; ++cc) {
        const int off = cc * 32;
        float4 a0[4], a1[4], b0[5], b1[5];
#pragma unroll
        for (int tn = 0; tn < 4; ++tn) {
            a0[tn] = *(const float4*)(pa[tn] + off);
            a1[tn] = *(const float4*)(pa[tn] + off + 4);
        }
#pragma unroll
        for (int j = 0; j < 5; ++j) {
            b0[j] = *(const float4*)(pb[j] + off);
            b1[j] = *(const float4*)(pb[j] + off + 4);
        }
        bf16x8 af[4], bfr[5];
#pragma unroll
        for (int tn = 0; tn < 4; ++tn) af[tn] = pack8(a0[tn], a1[tn], na[tn]);
#pragma unroll
        for (int j = 0; j < 5; ++j)  bfr[j] = pack8(b0[j], b1[j], nb[j]);
#pragma unroll
        for (int tn = 0; tn < 4; ++tn)
#pragma unroll
            for (int j = 0; j < 5; ++j)
                acc[tn][j] = __builtin_amdgcn_mfma_f32_16x16x32_bf16(af[tn], bfr[j], acc[tn][j], 0, 0, 0);
    }

    // ---- norms: reduce k-group partials (lanes lk=0..3 of same lr), invert
#pragma unroll
    for (int tn = 0; tn < 4; ++tn) {
        float v = na[tn];
        v += __shfl_xor(v, 16);
        v += __shfl_xor(v, 32);
        na[tn] = 1.0f / fmaxf(sqrtf(v), 1e-12f);   // inv-norm of row tn*16+lr
    }
#pragma unroll
    for (int j = 0; j < 5; ++j) {
        float v = nb[j];
        v += __shfl_xor(v, 16);
        v += __shfl_xor(v, 32);
        nb[j] = 1.0f / fmaxf(sqrtf(v), 1e-12f);    // inv-norm of row j*16+lr (= col m)
    }

    // ---- K = exp((sim-1)*10) into LDS. D layout: m = j*16+lr, n = tn*16+lk*4+rg
#pragma unroll
    for (int tn = 0; tn < 4; ++tn)
#pragma unroll
        for (int rg = 0; rg < 4; ++rg) {
            const int n = tn * 16 + lk * 4 + rg;
            const float ia = __shfl(na[tn], lk * 4 + rg);   // uniform shfl, lanes 0..15 hold it
            if (n < NP_) {
#pragma unroll
                for (int j = 0; j < 5; ++j) {
                    const int m = j * 16 + lr;
                    if (m < NT_) {
                        const float simv = acc[tn][j][rg] * ia * nb[j];
                        Kmat[n * 77 + m] = __expf((simv - 1.0f) * 10.0f);
                    }
                }
            }
        }

    // ---- move K into registers: row `lane` (for mv1/ot) + columns lane, 64+lane
    c_vec[lane] = 1.0f;
    if (lane < 16) c_vec[64 + lane] = 1.0f;

    const int nrow = (lane < NP_) ? lane : 0;
    float Kr[NT_];
#pragma unroll
    for (int m = 0; m < NT_; ++m)
        Kr[m] = (lane < NP_) ? Kmat[nrow * 77 + m] : 0.0f;

    const int col2 = (lane < 12) ? (64 + lane) : (NT_ - 1);
    float Kc[NP_], Kc2[NP_];
#pragma unroll
    for (int n = 0; n < NP_; ++n) {
        Kc[n]  = Kmat[n * 77 + lane];
        Kc2[n] = Kmat[n * 77 + col2];
    }

    // ---- Sinkhorn, wave-private.  Segment groupings replicate the old kernel
    // bit-for-bit: mv1 = ((s0+s1)+(s2+s3)) of 19-long serial sums; mv2 = (0..24)+(25..48);
    // err = (((g0+g1)+g2)+g3)/49 with g = binary-tree over 16 n's.
    float r_old = 1.0f;
    float err;
    int iter = 0;
    do {
        float y0 = 0.f, y1 = 0.f, y2 = 0.f, y3 = 0.f;
#pragma unroll
        for (int q = 0; q < 19; ++q) {
            const float4 cq = *(const float4*)(c_vec + q * 4);
#pragma unroll
            for (int e = 0; e < 4; ++e) {
                const int i = 4 * q + e;
                const float cv = f4get(cq, e);
                if (i < 19)      y0 += Kr[i] * cv;
                else if (i < 38) y1 += Kr[i] * cv;
                else if (i < 57) y2 += Kr[i] * cv;
                else             y3 += Kr[i] * cv;
            }
        }
        const float y  = (y0 + y1) + (y2 + y3);
        const float rn = (1.0f / 49.0f) / y;
        const float de = (lane < NP_) ? fabsf(rn - r_old) : 0.0f;
        r_old = rn;
        r_vec[lane] = rn;

        float e = de;
        e += __shfl_xor(e, 1);
        e += __shfl_xor(e, 2);
        e += __shfl_xor(e, 4);
        e += __shfl_xor(e, 8);
        const float g0 = __shfl(e, 0),  g1 = __shfl(e, 16);
        const float g2 = __shfl(e, 32), g3 = __shfl(e, 48);
        err = (((g0 + g1) + g2) + g3) * (1.0f / 49.0f);

        float z0 = 0.f, z1 = 0.f, w0 = 0.f, w1 = 0.f;
#pragma unroll
        for (int q = 0; q < 13; ++q) {
            const float4 rq = *(const float4*)(r_vec + q * 4);
#pragma unroll
            for (int e2 = 0; e2 < 4; ++e2) {
                const int n = 4 * q + e2;
                const float rv = f4get(rq, e2);
                if (n < 25)      { z0 += Kc[n] * rv; w0 += Kc2[n] * rv; }
                else if (n < 49) { z1 += Kc[n] * rv; w1 += Kc2[n] * rv; }
            }
        }
        c_vec[lane] = (1.0f / 76.0f) / (z0 + z1);
        if (lane < 12) c_vec[64 + lane] = (1.0f / 76.0f) / (w0 + w1);
        ++iter;
    } while (iter < 100 && err >= 1e-3f);

    // ---- ot partial: lane n sums its row;  sim = ln(K)/10 + 1
    float part = 0.f;
    if (lane < NP_) {
        const float rr = r_old;
#pragma unroll
        for (int q = 0; q < 19; ++q) {
            const float4 cq = *(const float4*)(c_vec + q * 4);
#pragma unroll
            for (int e2 = 0; e2 < 4; ++e2) {
                const float kv = Kr[4 * q + e2];
                part += rr * f4get(cq, e2) * kv * (__logf(kv) * 0.1f + 1.0f);
            }
        }
    }
#pragma unroll
    for (int o = 1; o < 64; o <<= 1) part += __shfl_xor(part, o);
    if (lane == 0) atomicAdd(out, part);
}

// ---------------------------------------------------------------------------
// Kernel 2: logits raw dots  L[i][j] = sum_k img[i][k]*txt[j][k], K=2304.
// 64x64 tiles, K split 8 ways (512 blocks -> 2 wg/CU), atomicAdd into ws.
// ---------------------------------------------------------------------------
__global__ __launch_bounds__(256) void gemm_logits(const float* __restrict__ A,
                                                   const float* __restrict__ Bm,
                                                   float* __restrict__ L) {
    __shared__ __attribute__((aligned(16))) float At[64 * 36];
    __shared__ __attribute__((aligned(16))) float Bt[64 * 36];
    const int tid = threadIdx.x;
    const int i0 = blockIdx.x * 64, j0 = blockIdx.y * 64, kbase = blockIdx.z * 288;
    const int ty = tid >> 4, tx = tid & 15;
    float accv[4][4] = {};
    for (int kc = 0; kc < 9; ++kc) {
        int kb = kbase + kc * 32;
#pragma unroll
        for (int t = 0; t < 2; ++t) {
            int idx = tid + t * 256;
            int row = idx >> 3, q = idx & 7;
            *(float4*)(At + row * 36 + q * 4) =
                *(const float4*)(A + (size_t)(i0 + row) * 2304 + kb + q * 4);
            *(float4*)(Bt + row * 36 + q * 4) =
                *(const float4*)(Bm + (size_t)(j0 + row) * 2304 + kb + q * 4);
        }
        __syncthreads();
#pragma unroll 8
        for (int k = 0; k < 32; ++k) {
            float ra[4], rb[4];
#pragma unroll
            for (int a = 0; a < 4; ++a) ra[a] = At[(ty + 16 * a) * 36 + k];
#pragma unroll
            for (int b = 0; b < 4; ++b) rb[b] = Bt[(tx + 16 * b) * 36 + k];
#pragma unroll
            for (int a = 0; a < 4; ++a)
#pragma unroll
                for (int b = 0; b < 4; ++b) accv[a][b] += ra[a] * rb[b];
        }
        __syncthreads();
    }
#pragma unroll
    for (int a = 0; a < 4; ++a)
#pragma unroll
        for (int b = 0; b < 4; ++b)
            atomicAdd(L + (size_t)(i0 + ty + 16 * a) * 512 + (j0 + tx + 16 * b), accv[a][b]);
}

// ---------------------------------------------------------------------------
// Kernel 3: CE with diagonal labels, both directions.  grid 512, block 256.
// ---------------------------------------------------------------------------
__device__ inline float blk_max(float v, float* sred, int wave, int lane) {
#pragma unroll
    for (int o = 1; o < 64; o <<= 1) v = fmaxf(v, __shfl_xor(v, o));
    if (lane == 0) sred[wave] = v;
    __syncthreads();
    v = fmaxf(fmaxf(sred[0], sred[1]), fmaxf(sred[2], sred[3]));
    __syncthreads();
    return v;
}
__device__ inline float blk_sum(float v, float* sred, int wave, int lane) {
#pragma unroll
    for (int o = 1; o < 64; o <<= 1) v += __shfl_xor(v, o);
    if (lane == 0) sred[wave] = v;
    __syncthreads();
    v = sred[0] + sred[1] + sred[2] + sred[3];
    __syncthreads();
    return v;
}

__global__ __launch_bounds__(256) void ce_kernel(const float* __restrict__ L,
                                                 const float* __restrict__ lsc,
                                                 float* __restrict__ out) {
    __shared__ float sred[4];
    const int i = blockIdx.x, tid = threadIdx.x;
    const int wave = tid >> 6, lane = tid & 63;
    const float s = lsc[0] * (1.0f / 3.0f);

    float xr0 = L[(size_t)i * 512 + tid] * s;
    float xr1 = L[(size_t)i * 512 + tid + 256] * s;
    float xc0 = L[(size_t)tid * 512 + i] * s;
    float xc1 = L[(size_t)(tid + 256) * 512 + i] * s;

    float mr = blk_max(fmaxf(xr0, xr1), sred, wave, lane);
    float sr = blk_sum(__expf(xr0 - mr) + __expf(xr1 - mr), sred, wave, lane);
    float lse_r = mr + __logf(sr);

    float mc = blk_max(fmaxf(xc0, xc1), sred, wave, lane);
    float sc = blk_sum(__expf(xc0 - mc) + __expf(xc1 - mc), sred, wave, lane);
    float lse_c = mc + __logf(sc);

    if (tid == 0) {
        float dii = L[(size_t)i * 512 + i] * s;
        atomicAdd(out, (lse_r + lse_c - 2.0f * dii) * (1.0f / 1024.0f));
    }
}

extern "C" void kernel_launch(void* const* d_in, const int* in_sizes, int n_in,
                              void* d_out, int out_size, void* d_ws, size_t ws_size,
                              hipStream_t stream) {
    const float* img = (const float*)d_in[0];   // [512,3,768]
    const float* txt = (const float*)d_in[1];   // [512,3,768]
    const float* lsc = (const float*)d_in[2];   // [1]
    const float* lif = (const float*)d_in[3];   // [512,3,49,768]
    const float* ltf = (const float*)d_in[4];   // [512,3,76,768]
    float* out = (float*)d_out;
    float* Lws = (float*)d_ws;                  // 512*512 f32 = 1 MB scratch

    hipMemsetAsync(out, 0, sizeof(float), stream);
    hipMemsetAsync(Lws, 0, 512 * 512 * sizeof(float), stream);

    hipLaunchKernelGGL(gemm_logits, dim3(8, 8, 8), dim3(256), 0, stream, img, txt, Lws);
    hipLaunchKernelGGL(sink_kernel, dim3(NB * NC), dim3(64), 0, stream, lif, ltf, out);
    hipLaunchKernelGGL(ce_kernel, dim3(512), dim3(256), 0, stream, Lws, lsc, out);
}